// Round 1
// baseline (534.181 us; speedup 1.0000x reference)
//
#include <hip/hip_runtime.h>

// Rpool (R-MAC): x[16,2048,48,64] fp32 -> out[16,2048,1,1]
// Region grid from _region_coords(48,64,3): idx=0, Wd=1, Hd=0
//   global:      rows[0,48) x cols[0,64)
//   l=1 (wl=48): rows[0,48)            x cols {0,16}+48
//   l=2 (wl=32): rows {0,16}+32        x cols {0,16,32}+32
//   l=3 (wl=24): rows {0,12,24}+24     x cols {0,13,26,40}+24
// Row windows: W0=[0,48) W1=[0,32) W2=[16,48) W3=[0,24) W4=[12,36) W5=[24,48)
// All are unions of row segments split at {0,12,16,24,32,36,48}:
//   s0=[0,12) s1=[12,16) s2=[16,24) s3=[24,32) s4=[32,36) s5=[36,48)

#define BB 16
#define CC 2048
#define HH 48
#define WW 64
#define NREG 21
#define MPB 16                       // maps per block (stage 1)
#define WSTRIDE 68                   // 64 cols + 4 pad (16B aligned, bank skew 4/win)
#define MSTRIDE (6 * WSTRIDE + 16)   // 424 floats (16B aligned, bank skew 8/map)
// LDS: 16 * 424 * 4 = 27136 B -> 6 blocks/CU (24 waves/CU)

__constant__ int c_reg_win[NREG] = {0,0,0, 1,1,1, 2,2,2, 3,3,3,3, 4,4,4,4, 5,5,5,5};
__constant__ int c_reg_j[NREG]   = {0,0,16, 0,16,32, 0,16,32, 0,13,26,40, 0,13,26,40, 0,13,26,40};
__constant__ int c_reg_wl[NREG]  = {64,48,48, 32,32,32, 32,32,32, 24,24,24,24, 24,24,24,24, 24,24,24,24};

__device__ __forceinline__ float4 max4(float4 a, float4 b) {
    return make_float4(fmaxf(a.x, b.x), fmaxf(a.y, b.y), fmaxf(a.z, b.z), fmaxf(a.w, b.w));
}

// Stage 1: 16 maps per block, 4 waves x 4 maps. Each lane owns 4 columns of one
// map and streams all 48 rows from global into 6 register segment-maxes.
// Only the 6x64 per-map column-max table touches LDS.
__global__ __launch_bounds__(256) void rpool_stage1(const float* __restrict__ x,
                                                    float* __restrict__ R) {
    __shared__ float cm[MPB * MSTRIDE];   // per-(map,win) column maxes, skewed

    const int t    = threadIdx.x;
    const int lane = t & 63;
    const int wid  = t >> 6;
    const int mloc = (wid << 2) + (lane >> 4);   // map within block, 0..15
    const int q    = lane & 15;                  // column quad, 0..15

    const int bid = blockIdx.x;
    const size_t g = (size_t)bid * MPB + mloc;   // global map index = b*2048 + c
    const float4* __restrict__ p = (const float4*)x + g * (HH * WW / 4) + q;

    // ---- stream 48 rows, accumulate 6 row-segment maxes in registers ----
    float4 s0, s1, s2, s3, s4, s5;
    #pragma unroll
    for (int r = 0; r < HH; ++r) {
        float4 v = p[(size_t)r * 16];
        if      (r < 12) s0 = (r == 0)  ? v : max4(s0, v);
        else if (r < 16) s1 = (r == 12) ? v : max4(s1, v);
        else if (r < 24) s2 = (r == 16) ? v : max4(s2, v);
        else if (r < 32) s3 = (r == 24) ? v : max4(s3, v);
        else if (r < 36) s4 = (r == 32) ? v : max4(s4, v);
        else             s5 = (r == 36) ? v : max4(s5, v);
    }

    // ---- combine segments into the 6 row-window column maxes ----
    float4 a  = max4(s0, s1);
    float4 bb = max4(s2, s3);
    float4 cc = max4(s4, s5);
    float4 w1 = max4(a, bb);                       // [0,32)
    float4 w0 = max4(w1, cc);                      // [0,48)
    float4 w2 = max4(bb, cc);                      // [16,48)
    float4 w3 = max4(a, s2);                       // [0,24)
    float4 w4 = max4(max4(s1, s2), max4(s3, s4));  // [12,36)
    float4 w5 = max4(s3, cc);                      // [24,48)

    float* base = cm + mloc * MSTRIDE + 4 * q;
    *(float4*)(base + 0 * WSTRIDE) = w0;
    *(float4*)(base + 1 * WSTRIDE) = w1;
    *(float4*)(base + 2 * WSTRIDE) = w2;
    *(float4*)(base + 3 * WSTRIDE) = w3;
    *(float4*)(base + 4 * WSTRIDE) = w4;
    *(float4*)(base + 5 * WSTRIDE) = w5;
    __syncthreads();

    // ---- 21 regions x 16 maps = 336 tasks; reduce column window, store ----
    const int bb_idx = bid >> 7;              // batch
    const int cbase  = (bid & 127) << 4;      // channel base (block = 16 consecutive c)
    for (int task = t; task < MPB * NREG; task += 256) {
        const int m   = task / NREG;
        const int rg  = task - m * NREG;
        const float* row = cm + m * MSTRIDE + c_reg_win[rg] * WSTRIDE + c_reg_j[rg];
        const int wl  = c_reg_wl[rg];
        float mx = row[0];
        for (int k = 1; k < wl; ++k) mx = fmaxf(mx, row[k]);
        R[(((size_t)bb_idx * NREG + rg) << 11) + cbase + m] = mx;
    }
}

// Stage 2: one block of 1024 threads per batch. float2 loads, per-region values
// kept in registers between the norm pass and the weighted-sum pass.
__global__ __launch_bounds__(1024) void rpool_stage2(const float* __restrict__ R,
                                                     float* __restrict__ out) {
    const int b    = blockIdx.x;
    const int t    = threadIdx.x;
    const int lane = t & 63;
    const int wave = t >> 6;                  // 0..15

    __shared__ float partials[NREG][16];
    __shared__ float scale[NREG];
    __shared__ float osq_part[16];

    const float2* __restrict__ Rb = (const float2*)(R + (size_t)b * NREG * CC);

    // per-region sum of squares over channels (values cached in registers)
    float2 vv[NREG];
    #pragma unroll
    for (int r = 0; r < NREG; ++r) {
        float2 v = Rb[r * (CC / 2) + t];
        vv[r] = v;
        float acc = v.x * v.x + v.y * v.y;
        #pragma unroll
        for (int off = 32; off; off >>= 1) acc += __shfl_down(acc, off);
        if (lane == 0) partials[r][wave] = acc;
    }
    __syncthreads();
    if (t < NREG) {
        float s = 0.f;
        #pragma unroll
        for (int w = 0; w < 16; ++w) s += partials[t][w];
        scale[t] = 1.0f / (sqrtf(s) + 1e-6f);
    }
    __syncthreads();

    // normalized sum over regions + final L2 norm
    float2 acc = make_float2(0.f, 0.f);
    #pragma unroll
    for (int r = 0; r < NREG; ++r) {
        acc.x += vv[r].x * scale[r];
        acc.y += vv[r].y * scale[r];
    }
    float osq = acc.x * acc.x + acc.y * acc.y;
    #pragma unroll
    for (int off = 32; off; off >>= 1) osq += __shfl_down(osq, off);
    if (lane == 0) osq_part[wave] = osq;
    __syncthreads();
    float tot = 0.f;
    #pragma unroll
    for (int w = 0; w < 16; ++w) tot += osq_part[w];
    const float oscale = 1.0f / (sqrtf(tot) + 1e-6f);
    ((float2*)(out + (size_t)b * CC))[t] = make_float2(acc.x * oscale, acc.y * oscale);
}

extern "C" void kernel_launch(void* const* d_in, const int* in_sizes, int n_in,
                              void* d_out, int out_size, void* d_ws, size_t ws_size,
                              hipStream_t stream) {
    const float* x = (const float*)d_in[0];
    float* R = (float*)d_ws;                 // [16][21][2048] = 2.75 MB scratch
    float* out = (float*)d_out;

    rpool_stage1<<<BB * CC / MPB, 256, 0, stream>>>(x, R);
    rpool_stage2<<<BB, 1024, 0, stream>>>(R, out);
}